// Round 4
// baseline (267.217 us; speedup 1.0000x reference)
//
#include <hip/hip_runtime.h>
#include <math.h>

// Problem constants
#define NB    64     // batch
#define NQn   256    // queries
#define NNn   512    // nodes
#define HDn   128    // H*D = EMB
#define LOG2E 1.44269504088896340736f
#define INV_SQRT_EMB 0.08838834764831845f   // 1/sqrt(128)

__device__ __forceinline__ float4 ldg4(const float* p) {
    return *reinterpret_cast<const float4*>(p);
}

// ---------------------------------------------------------------------------
// proj_kernel v3: Y[R x 128] = X[R x 128] @ W[128 x 128] (+ attr rank-1, +bias)
// Block 512 thr (8 waves) on a 64-row x 64-col tile -> 2 blocks/CU (64KB LDS)
// = 4 waves/EU (was 2 with 256 thr). acc[2][4]/thread; 32 FMA : 6 ds_read_b128
// per k4 iter. Optional second pass (W1/Y1) reuses the staged X tile (K,V).
// XOR-swizzled float4 blocks keep all LDS reads <=2-way (free).
// ---------------------------------------------------------------------------
__global__ __launch_bounds__(512, 4)
void proj_kernel(const float* __restrict__ X,
                 const float* __restrict__ W0, const float* __restrict__ W1,
                 const float* __restrict__ wrow, const float* __restrict__ attr,
                 const float* __restrict__ bias,
                 float* __restrict__ Y0, float* __restrict__ Y1)
{
    __shared__ float Xs[64 * 128];
    __shared__ float Wt[64 * 128];
    const int tid = threadIdx.x;
    const int rg = tid >> 4;          // 0..31 (rows rg, rg+32)
    const int cg = tid & 15;          // 0..15 (cols cg+16c)
    const int rowblk = blockIdx.x * 64;
    const int colbase = blockIdx.y * 64;

    // stage X tile (swizzled), coalesced float4 loads: 4 per thread
    #pragma unroll
    for (int i = 0; i < 4; ++i) {
        int idx = tid + 512 * i;      // f4 index in [0,2048)
        int r = idx >> 5;             // 32 f4 per row
        int c4 = idx & 31;
        float4 v = ldg4(X + (rowblk + r) * 128 + c4 * 4);
        *reinterpret_cast<float4*>(&Xs[r * 128 + ((c4 ^ (r & 7)) << 2)]) = v;
    }

    for (int pass = 0; pass < 2; ++pass) {
        if (pass && (W1 == nullptr)) break;
        const float* W = pass ? W1 : W0;
        float* Y = pass ? Y1 : Y0;
        __syncthreads();   // pass0: X staged; pass1: compute done before Wt overwrite
        // stage Wt[c][k] = W[k][colbase+c], swizzled on k4: 16 scalars/thread
        #pragma unroll
        for (int i = 0; i < 16; ++i) {
            int idx = tid + 512 * i;  // 8192 scalars
            int k = idx >> 6;         // 0..127
            int c = idx & 63;         // 0..63
            float w = W[k * 128 + colbase + c];
            Wt[c * 128 + ((((k >> 2) ^ (c & 7)) << 2) | (k & 3))] = w;
        }
        __syncthreads();

        float acc[2][4];
        #pragma unroll
        for (int r = 0; r < 2; ++r)
            #pragma unroll
            for (int c = 0; c < 4; ++c) acc[r][c] = 0.f;

        const int rsw = rg & 7;       // (rg+32r)&7 == rg&7
        const int csw = cg & 7;       // (cg+16c)&7 == cg&7
        #pragma unroll 8
        for (int k4 = 0; k4 < 32; ++k4) {
            float4 a[2], bv[4];
            #pragma unroll
            for (int r = 0; r < 2; ++r)
                a[r] = *reinterpret_cast<const float4*>(&Xs[(rg + 32 * r) * 128 + ((k4 ^ rsw) << 2)]);
            #pragma unroll
            for (int c = 0; c < 4; ++c)
                bv[c] = *reinterpret_cast<const float4*>(&Wt[(cg + 16 * c) * 128 + ((k4 ^ csw) << 2)]);
            #pragma unroll
            for (int r = 0; r < 2; ++r)
                #pragma unroll
                for (int c = 0; c < 4; ++c)
                    acc[r][c] += a[r].x * bv[c].x + a[r].y * bv[c].y
                               + a[r].z * bv[c].z + a[r].w * bv[c].w;
        }

        if (attr != nullptr) {        // 129th input row (attr concat) for Wq_last
            #pragma unroll
            for (int r = 0; r < 2; ++r) {
                float av = attr[rowblk + rg + 32 * r];
                #pragma unroll
                for (int c = 0; c < 4; ++c)
                    acc[r][c] += av * wrow[colbase + cg + 16 * c];
            }
        }
        #pragma unroll
        for (int r = 0; r < 2; ++r) {
            int row = rowblk + rg + 32 * r;
            #pragma unroll
            for (int c = 0; c < 4; ++c) {
                int col = colbase + cg + 16 * c;
                float o = acc[r][c];
                if (bias != nullptr) o += bias[col];
                Y[row * 128 + col] = o;
            }
        }
    }
}

// ---------------------------------------------------------------------------
// attn_kernel v4: LDS-staged masked MHA with register-pipelined hot loop.
// Block 512 thr = 8 waves = 8 heads; grid (64 b, 4 q-tiles, 2 node-splits).
// Per iteration 2 nodes: 16 NAMED float4 ds_read_b128 (K_A,K_B,V_A,V_B) all
// issued before any consumer -> ~110 live VGPRs, loads fully in flight while
// the previous FMA block runs (fixes r3's VGPR=44 4-reg window serialization).
// Fixed-shift softmax (scores sigma~0.33, validated r1-r3): p = exp2(dot+m),
// 0.25*log2e folded into q; mask 0/-inf transposed in LDS, conflict-free.
// ---------------------------------------------------------------------------
__global__ __launch_bounds__(512, 4)
void attn_kernel(const float* __restrict__ Q, const float* __restrict__ K,
                 const float* __restrict__ V, const float* __restrict__ mask,
                 float* __restrict__ P0, float* __restrict__ P1,
                 float* __restrict__ L0, float* __restrict__ L1)
{
    __shared__ float Ks[32 * 128];    // 16KB
    __shared__ float Vs[32 * 128];    // 16KB
    __shared__ float Ms[32 * 64];     //  8KB, [n][q ^ n]
    const int tid  = threadIdx.x;
    const int lane = tid & 63;
    const int h    = tid >> 6;        // wave = head
    const int b    = blockIdx.x;
    const int qt   = blockIdx.y;
    const int ns   = blockIdx.z;
    const int q    = qt * 64 + lane;
    const int nb   = ns * 256;

    // q fragment, pre-scaled by 0.25*log2e
    float qv[16];
    {
        const float* qp = Q + (b * NQn + q) * 128 + h * 16;
        const float sc = 0.25f * LOG2E;
        float4 t0 = ldg4(qp), t1 = ldg4(qp + 4), t2 = ldg4(qp + 8), t3 = ldg4(qp + 12);
        qv[0]=t0.x*sc;  qv[1]=t0.y*sc;  qv[2]=t0.z*sc;  qv[3]=t0.w*sc;
        qv[4]=t1.x*sc;  qv[5]=t1.y*sc;  qv[6]=t1.z*sc;  qv[7]=t1.w*sc;
        qv[8]=t2.x*sc;  qv[9]=t2.y*sc;  qv[10]=t2.z*sc; qv[11]=t2.w*sc;
        qv[12]=t3.x*sc; qv[13]=t3.y*sc; qv[14]=t3.z*sc; qv[15]=t3.w*sc;
    }

    float out[16];
    #pragma unroll
    for (int d = 0; d < 16; ++d) out[d] = 0.f;
    float lsum = 0.f;

    const int srow = tid >> 3;        // mask stage: q row 0..63
    const int sn4  = tid & 7;         // f4 within 32-node tile

    for (int t = 0; t < 8; ++t) {
        const int n0 = nb + t * 32;
        __syncthreads();
        {   // stage K,V (2 f4/thread each, coalesced), mask (1 f4 -> transposed)
            int i0 = tid, i1 = tid + 512;          // f4 idx in [0,1024)
            const float* kg = K + (b * NNn + n0) * 128;
            const float* vg = V + (b * NNn + n0) * 128;
            float4 k0 = ldg4(kg + i0 * 4), k1 = ldg4(kg + i1 * 4);
            float4 v0 = ldg4(vg + i0 * 4), v1 = ldg4(vg + i1 * 4);
            float4 mk = ldg4(mask + (b * NQn + qt * 64 + srow) * NNn + n0 + sn4 * 4);
            *reinterpret_cast<float4*>(&Ks[i0 * 4]) = k0;
            *reinterpret_cast<float4*>(&Ks[i1 * 4]) = k1;
            *reinterpret_cast<float4*>(&Vs[i0 * 4]) = v0;
            *reinterpret_cast<float4*>(&Vs[i1 * 4]) = v1;
            float mks[4] = {mk.x, mk.y, mk.z, mk.w};
            #pragma unroll
            for (int j = 0; j < 4; ++j) {
                int n = sn4 * 4 + j;
                Ms[n * 64 + (srow ^ n)] = mks[j];
            }
        }
        __syncthreads();

        const float* kbase = &Ks[h * 16];
        const float* vbase = &Vs[h * 16];
        for (int g = 0; g < 16; ++g) {            // 2 nodes per iteration
            const int nA = g * 2, nB = g * 2 + 1;
            const float* krA = kbase + nA * 128;
            const float* krB = kbase + nB * 128;
            const float* vrA = vbase + nA * 128;
            const float* vrB = vbase + nB * 128;
            // --- all 16 loads issued before any consumer ---
            float4 ka0 = *reinterpret_cast<const float4*>(krA);
            float4 ka1 = *reinterpret_cast<const float4*>(krA + 4);
            float4 ka2 = *reinterpret_cast<const float4*>(krA + 8);
            float4 ka3 = *reinterpret_cast<const float4*>(krA + 12);
            float4 kb0 = *reinterpret_cast<const float4*>(krB);
            float4 kb1 = *reinterpret_cast<const float4*>(krB + 4);
            float4 kb2 = *reinterpret_cast<const float4*>(krB + 8);
            float4 kb3 = *reinterpret_cast<const float4*>(krB + 12);
            float4 va0 = *reinterpret_cast<const float4*>(vrA);
            float4 va1 = *reinterpret_cast<const float4*>(vrA + 4);
            float4 va2 = *reinterpret_cast<const float4*>(vrA + 8);
            float4 va3 = *reinterpret_cast<const float4*>(vrA + 12);
            float4 vb0 = *reinterpret_cast<const float4*>(vrB);
            float4 vb1 = *reinterpret_cast<const float4*>(vrB + 4);
            float4 vb2 = *reinterpret_cast<const float4*>(vrB + 8);
            float4 vb3 = *reinterpret_cast<const float4*>(vrB + 12);
            float mvA = Ms[nA * 64 + (lane ^ nA)];
            float mvB = Ms[nB * 64 + (lane ^ nB)];
            // --- dots ---
            float aP = qv[0]*ka0.x + qv[1]*ka0.y + qv[2]*ka0.z + qv[3]*ka0.w;
            float aQ = qv[4]*ka1.x + qv[5]*ka1.y + qv[6]*ka1.z + qv[7]*ka1.w;
            float aR = qv[8]*ka2.x + qv[9]*ka2.y + qv[10]*ka2.z + qv[11]*ka2.w;
            float aS = qv[12]*ka3.x + qv[13]*ka3.y + qv[14]*ka3.z + qv[15]*ka3.w;
            float bP = qv[0]*kb0.x + qv[1]*kb0.y + qv[2]*kb0.z + qv[3]*kb0.w;
            float bQ = qv[4]*kb1.x + qv[5]*kb1.y + qv[6]*kb1.z + qv[7]*kb1.w;
            float bR = qv[8]*kb2.x + qv[9]*kb2.y + qv[10]*kb2.z + qv[11]*kb2.w;
            float bS = qv[12]*kb3.x + qv[13]*kb3.y + qv[14]*kb3.z + qv[15]*kb3.w;
            float sA = ((aP + aQ) + (aR + aS)) + mvA;   // -inf -> p=0
            float sB = ((bP + bQ) + (bR + bS)) + mvB;
            float pA = exp2f(sA);
            float pB = exp2f(sB);
            lsum += pA + pB;
            // --- PV ---
            out[0]  += pA*va0.x + pB*vb0.x;  out[1]  += pA*va0.y + pB*vb0.y;
            out[2]  += pA*va0.z + pB*vb0.z;  out[3]  += pA*va0.w + pB*vb0.w;
            out[4]  += pA*va1.x + pB*vb1.x;  out[5]  += pA*va1.y + pB*vb1.y;
            out[6]  += pA*va1.z + pB*vb1.z;  out[7]  += pA*va1.w + pB*vb1.w;
            out[8]  += pA*va2.x + pB*vb2.x;  out[9]  += pA*va2.y + pB*vb2.y;
            out[10] += pA*va2.z + pB*vb2.z;  out[11] += pA*va2.w + pB*vb2.w;
            out[12] += pA*va3.x + pB*vb3.x;  out[13] += pA*va3.y + pB*vb3.y;
            out[14] += pA*va3.z + pB*vb3.z;  out[15] += pA*va3.w + pB*vb3.w;
        }
    }

    float* P = ns ? P1 : P0;
    float* L = ns ? L1 : L0;
    float* op = P + (b * NQn + q) * 128 + h * 16;
    *reinterpret_cast<float4*>(op)      = make_float4(out[0],  out[1],  out[2],  out[3]);
    *reinterpret_cast<float4*>(op + 4)  = make_float4(out[4],  out[5],  out[6],  out[7]);
    *reinterpret_cast<float4*>(op + 8)  = make_float4(out[8],  out[9],  out[10], out[11]);
    *reinterpret_cast<float4*>(op + 12) = make_float4(out[12], out[13], out[14], out[15]);
    L[(b * NQn + q) * 8 + h] = lsum;
}

// ---------------------------------------------------------------------------
// attn_merge: ATT = (P0+P1)/(L0+L1); fully-masked rows -> V[b][node 0] slice.
// P0 aliases ATT (per-thread read-then-write, safe). grid 2048 x 256.
// ---------------------------------------------------------------------------
__global__ __launch_bounds__(256, 4)
void attn_merge(const float* __restrict__ P0, const float* __restrict__ P1,
                const float* __restrict__ L0, const float* __restrict__ L1,
                const float* __restrict__ V, float* __restrict__ ATT)
{
    const int idx = blockIdx.x * 256 + threadIdx.x;  // f4 index over B*NQ*32
    const int row = idx >> 5;                        // b*NQ + q
    const int f4i = idx & 31;
    const int hh  = f4i >> 2;
    const int b   = row >> 8;
    const float l = L0[row * 8 + hh] + L1[row * 8 + hh];
    float4 a = ldg4(P0 + row * 128 + f4i * 4);
    float4 c = ldg4(P1 + row * 128 + f4i * 4);
    float4 r;
    if (l == 0.0f) {
        r = ldg4(V + (size_t)b * NNn * 128 + f4i * 4);   // node 0, weights = one-hot
    } else {
        float inv = __builtin_amdgcn_rcpf(l);
        r = make_float4((a.x + c.x) * inv, (a.y + c.y) * inv,
                        (a.z + c.z) * inv, (a.w + c.w) * inv);
    }
    *reinterpret_cast<float4*>(ATT + row * 128 + f4i * 4) = r;
}

// ---------------------------------------------------------------------------
// final_kernel v2: probs = softmax(10*tanh(MH @ EN^T / sqrt(128)) + mask).
// q-tile 32 -> grid 512 blocks = 2 blocks/CU (was 1). Block 512 thr: 1 q-row
// per thread (qg 0..31), mg 16 lanes over m. EN m-tiles of 128 in 64KB
// swizzled LDS. Logits bounded by tanh clip -> fixed shift; pr[32] static.
// ---------------------------------------------------------------------------
__global__ __launch_bounds__(512, 4)
void final_kernel(const float* __restrict__ MH, const float* __restrict__ EN,
                  const float* __restrict__ mask, float* __restrict__ OUT)
{
    __shared__ float ENs[128 * 128];
    const int tid = threadIdx.x;
    const int qg = tid >> 4;          // 0..31 (1 q-row each)
    const int mg = tid & 15;          // 0..15 (m = mg + 16c)
    const int b  = blockIdx.x >> 3;
    const int q0 = (blockIdx.x & 7) * 32;

    const float* mhrow = MH + (b * NQn + q0 + qg) * 128;
    float pr[32];                     // unnormalized exp(logit); statically indexed
    float psum = 0.f;
    const int msw = mg & 7;

    #pragma unroll
    for (int t = 0; t < 4; ++t) {     // m-tiles of 128
        const int m0 = t * 128;
        __syncthreads();              // previous tile fully consumed
        #pragma unroll
        for (int i = 0; i < 8; ++i) {
            int idx = tid + 512 * i;  // f4 index in [0,4096)
            int r = idx >> 5;
            int c4 = idx & 31;
            float4 v = ldg4(EN + (b * NNn + m0 + r) * 128 + c4 * 4);
            *reinterpret_cast<float4*>(&ENs[r * 128 + ((c4 ^ (r & 7)) << 2)]) = v;
        }
        __syncthreads();

        float acc[8];
        #pragma unroll
        for (int c = 0; c < 8; ++c) acc[c] = 0.f;

        #pragma unroll 4
        for (int k4 = 0; k4 < 32; ++k4) {
            float4 a0 = ldg4(mhrow + k4 * 4);      // L1-resident, 16-lane broadcast
            float4 bv[8];
            #pragma unroll
            for (int c = 0; c < 8; ++c)
                bv[c] = *reinterpret_cast<const float4*>(&ENs[(mg + 16 * c) * 128 + ((k4 ^ msw) << 2)]);
            #pragma unroll
            for (int c = 0; c < 8; ++c)
                acc[c] += a0.x*bv[c].x + a0.y*bv[c].y + a0.z*bv[c].z + a0.w*bv[c].w;
        }

        // epilogue: logit-10 = mask - 20/(exp(2*s2)+1);  p = exp2((.)*log2e)
        const float* mrow = mask + (b * NQn + q0 + qg) * NNn + m0;
        #pragma unroll
        for (int c = 0; c < 8; ++c) {
            int m = mg + 16 * c;
            float s2 = acc[c] * INV_SQRT_EMB;
            float e  = exp2f(s2 * (2.0f * LOG2E));         // saturates at extremes
            float rc = __builtin_amdgcn_rcpf(e + 1.0f);
            float mv = mrow[m];                            // coalesced 64B segments
            float pv = exp2f((mv - 20.0f * rc) * LOG2E);   // mv=-inf -> pv=0
            pr[t * 8 + c] = pv;
            psum += pv;
        }
    }

    // row-sum across the 16 mg lanes (lanes qg*16..qg*16+15 are consecutive)
    {
        float s = psum;
        s += __shfl_xor(s, 1);
        s += __shfl_xor(s, 2);
        s += __shfl_xor(s, 4);
        s += __shfl_xor(s, 8);
        psum = s;
    }

    float* orow = OUT + (b * NQn + q0 + qg) * NNn;
    if (psum == 0.0f) {               // fully-masked row -> one-hot at m=0
        #pragma unroll
        for (int t = 0; t < 4; ++t)
            #pragma unroll
            for (int c = 0; c < 8; ++c) {
                int m = t * 128 + mg + 16 * c;
                orow[m] = (m == 0) ? 1.0f : 0.0f;
            }
    } else {
        float inv = __builtin_amdgcn_rcpf(psum);
        #pragma unroll
        for (int t = 0; t < 4; ++t)
            #pragma unroll
            for (int c = 0; c < 8; ++c)
                orow[t * 128 + mg + 16 * c] = pr[t * 8 + c] * inv;
    }
}

// ---------------------------------------------------------------------------
extern "C" void kernel_launch(void* const* d_in, const int* in_sizes, int n_in,
                              void* d_out, int out_size, void* d_ws, size_t ws_size,
                              hipStream_t stream) {
    const float* enc_last  = (const float*)d_in[0];   // [B,NQ,128]
    const float* attr      = (const float*)d_in[1];   // [B,NQ,1]
    const float* enc_nodes = (const float*)d_in[2];   // [B,NN,128]
    const float* mask      = (const float*)d_in[3];   // [B,NQ,NN]
    const float* Wq        = (const float*)d_in[4];   // [129,128]
    const float* Wk        = (const float*)d_in[5];   // [128,128]
    const float* Wv        = (const float*)d_in[6];   // [128,128]
    const float* Wcomb     = (const float*)d_in[7];   // [128,128]
    const float* bcomb     = (const float*)d_in[8];   // [128]
    float* out = (float*)d_out;

    float* Kbuf = (float*)d_ws;                         // [B*NN,128] 16.8MB
    float* Vbuf = Kbuf + (size_t)NB * NNn * 128;        // [B*NN,128] 16.8MB
    float* Qbuf = Vbuf + (size_t)NB * NNn * 128;        // [B*NQ,128]  8.4MB
    float* ATT  = Qbuf + (size_t)NB * NQn * 128;        // [B*NQ,128]  8.4MB (= P0)
    float* MH   = ATT  + (size_t)NB * NQn * 128;        // [B*NQ,128]  8.4MB
    float* P1   = MH   + (size_t)NB * NQn * 128;        // [B*NQ,128]  8.4MB
    float* L0   = P1   + (size_t)NB * NQn * 128;        // [B*NQ,8]    0.5MB
    float* L1   = L0   + (size_t)NB * NQn * 8;          // [B*NQ,8]    0.5MB

    // K,V projections (dual-pass over shared X tile)
    proj_kernel<<<dim3(NB * NNn / 64, 2), 512, 0, stream>>>(
        enc_nodes, Wk, Wv, nullptr, nullptr, nullptr, Kbuf, Vbuf);
    // Q projection (concat attr handled as rank-1 term with Wq row 128)
    proj_kernel<<<dim3(NB * NQn / 64, 2), 512, 0, stream>>>(
        enc_last, Wq, nullptr, Wq + 128 * 128, attr, nullptr, Qbuf, nullptr);
    // masked multi-head attention (node-split partials)
    attn_kernel<<<dim3(NB, 4, 2), 512, 0, stream>>>(
        Qbuf, Kbuf, Vbuf, mask, ATT, P1, L0, L1);
    // merge node-splits (P0 aliases ATT)
    attn_merge<<<dim3(NB * NQn * 32 / 256), 256, 0, stream>>>(
        ATT, P1, L0, L1, Vbuf, ATT);
    // combine projection + bias
    proj_kernel<<<dim3(NB * NQn / 64, 2), 512, 0, stream>>>(
        ATT, Wcomb, nullptr, nullptr, nullptr, bcomb, MH, nullptr);
    // compatibility score + tanh clip + masked softmax
    final_kernel<<<dim3(NB * NQn / 32), 512, 0, stream>>>(
        MH, enc_nodes, mask, out);
}

// Round 5
// 246.731 us; speedup vs baseline: 1.0830x; 1.0830x over previous
//
#include <hip/hip_runtime.h>
#include <math.h>

// Problem constants
#define NB    64     // batch
#define NQn   256    // queries
#define NNn   512    // nodes
#define HDn   128    // H*D = EMB
#define LOG2E 1.44269504088896340736f
#define INV_SQRT_EMB 0.08838834764831845f   // 1/sqrt(128)

__device__ __forceinline__ float4 ldg4(const float* p) {
    return *reinterpret_cast<const float4*>(p);
}

// ---------------------------------------------------------------------------
// mask_transpose: mask[b][q][n] (f32, 0 / -inf) -> maskT8[b][n][q] (u8, 0/1).
// Block 256 = 4 waves; wave w handles 16 q-rows, lane = n. Reads coalesced
// 256B segments; each thread packs 16 bytes -> one uint4 store.
// ---------------------------------------------------------------------------
__global__ __launch_bounds__(256, 4)
void mask_transpose(const float* __restrict__ mask, unsigned char* __restrict__ maskT8)
{
    const int tid = threadIdx.x;
    const int w   = tid >> 6;                       // q-subgroup of 16
    const int n   = blockIdx.z * 64 + (tid & 63);
    const int b   = blockIdx.x;
    const int q0  = blockIdx.y * 64 + w * 16;
    unsigned int u[4] = {0u, 0u, 0u, 0u};
    #pragma unroll
    for (int j = 0; j < 16; ++j) {
        float v = mask[((size_t)(b * NQn + q0 + j)) * NNn + n];
        unsigned int bit = (v != 0.0f) ? 1u : 0u;   // mask is exactly 0 or -inf
        u[j >> 2] |= bit << (8 * (j & 3));
    }
    *reinterpret_cast<uint4*>(maskT8 + ((size_t)(b * NNn + n)) * NQn + q0) =
        make_uint4(u[0], u[1], u[2], u[3]);
}

// ---------------------------------------------------------------------------
// proj_kernel (R3 version): Y[R x 128] = X[R x 128] @ W[128 x 128]
// (+ attr*wrow rank-1, + bias). grid (R/64, 2 col-halves), block 256 (4 waves),
// 2 blocks/CU. 4x4 acc/thread: 64 FMA per 8 LDS b128 reads (8:1).
// Optional second pass (W1/Y1) reuses the staged X tile (used for K and V).
// ---------------------------------------------------------------------------
__global__ __launch_bounds__(256, 2)
void proj_kernel(const float* __restrict__ X,
                 const float* __restrict__ W0, const float* __restrict__ W1,
                 const float* __restrict__ wrow, const float* __restrict__ attr,
                 const float* __restrict__ bias,
                 float* __restrict__ Y0, float* __restrict__ Y1)
{
    __shared__ float Xs[64 * 128];
    __shared__ float Wt[64 * 128];
    const int tid = threadIdx.x;
    const int rg = tid >> 4;          // 0..15
    const int cg = tid & 15;          // 0..15
    const int rowblk = blockIdx.x * 64;
    const int colbase = blockIdx.y * 64;

    #pragma unroll
    for (int i = 0; i < 8; ++i) {
        int idx = tid + 256 * i;      // f4 index in [0,2048)
        int r = idx >> 5;             // 32 f4 per row
        int c4 = idx & 31;
        float4 v = ldg4(X + (rowblk + r) * 128 + c4 * 4);
        *reinterpret_cast<float4*>(&Xs[r * 128 + ((c4 ^ (r & 7)) << 2)]) = v;
    }

    for (int pass = 0; pass < 2; ++pass) {
        if (pass && (W1 == nullptr)) break;
        const float* W = pass ? W1 : W0;
        float* Y = pass ? Y1 : Y0;
        __syncthreads();
        #pragma unroll
        for (int i = 0; i < 32; ++i) {
            int idx = tid + 256 * i;  // 8192 scalars
            int k = idx >> 6;         // 0..127
            int c = idx & 63;         // 0..63
            float w = W[k * 128 + colbase + c];
            Wt[c * 128 + ((((k >> 2) ^ (c & 7)) << 2) | (k & 3))] = w;
        }
        __syncthreads();

        float acc[4][4];
        #pragma unroll
        for (int r = 0; r < 4; ++r)
            #pragma unroll
            for (int c = 0; c < 4; ++c) acc[r][c] = 0.f;

        const int rsw = rg & 7;
        const int csw = cg & 7;
        #pragma unroll 8
        for (int k4 = 0; k4 < 32; ++k4) {
            float4 a[4], bv[4];
            #pragma unroll
            for (int r = 0; r < 4; ++r)
                a[r] = *reinterpret_cast<const float4*>(&Xs[(rg + 16 * r) * 128 + ((k4 ^ rsw) << 2)]);
            #pragma unroll
            for (int c = 0; c < 4; ++c)
                bv[c] = *reinterpret_cast<const float4*>(&Wt[(cg + 16 * c) * 128 + ((k4 ^ csw) << 2)]);
            #pragma unroll
            for (int r = 0; r < 4; ++r)
                #pragma unroll
                for (int c = 0; c < 4; ++c)
                    acc[r][c] += a[r].x * bv[c].x + a[r].y * bv[c].y
                               + a[r].z * bv[c].z + a[r].w * bv[c].w;
        }

        if (attr != nullptr) {
            #pragma unroll
            for (int r = 0; r < 4; ++r) {
                float av = attr[rowblk + rg + 16 * r];
                #pragma unroll
                for (int c = 0; c < 4; ++c)
                    acc[r][c] += av * wrow[colbase + cg + 16 * c];
            }
        }
        #pragma unroll
        for (int r = 0; r < 4; ++r) {
            int row = rowblk + rg + 16 * r;
            #pragma unroll
            for (int c = 0; c < 4; ++c) {
                int col = colbase + cg + 16 * c;
                float o = acc[r][c];
                if (bias != nullptr) o += bias[col];
                Y[row * 128 + col] = o;
            }
        }
    }
}

// ---------------------------------------------------------------------------
// attn_kernel v5: 4 q-rows PER LANE -> 4x reuse of every K/V LDS broadcast.
// Block 512 = 8 waves = 8 heads, covering ALL 256 q (q = 4*lane+qq).
// grid (64 b, 4 node-splits of 128). K/V staged in LDS in 32-node tiles
// (broadcast reads, conflict-free). Mask read as ONE dword/node/lane from the
// pre-transposed u8 tensor (coalesced); masked -> p=0 via cndmask (no -inf).
// Fixed-shift softmax (validated r1-r4): p = exp2(dot*0.25*log2e).
// Partials are linear; merged by attn_merge.
// ---------------------------------------------------------------------------
__global__ __launch_bounds__(512, 2)
void attn_kernel(const float* __restrict__ Q, const float* __restrict__ K,
                 const float* __restrict__ V, const unsigned int* __restrict__ maskTu,
                 float* __restrict__ P0, float* __restrict__ P1,
                 float* __restrict__ P2, float* __restrict__ P3,
                 float* __restrict__ L0, float* __restrict__ L1,
                 float* __restrict__ L2, float* __restrict__ L3)
{
    __shared__ float Ks[32 * 128];    // 16KB
    __shared__ float Vs[32 * 128];    // 16KB
    const int tid  = threadIdx.x;
    const int lane = tid & 63;
    const int h    = tid >> 6;        // wave = head
    const int b    = blockIdx.x;
    const int ns   = blockIdx.y;
    const int nbase = ns * 128;

    // 4 q-fragments, pre-scaled by 0.25*log2e
    float qv[4][16];
    {
        const float sc = 0.25f * LOG2E;
        #pragma unroll
        for (int qq = 0; qq < 4; ++qq) {
            const float* qp = Q + ((size_t)(b * NQn + 4 * lane + qq)) * 128 + h * 16;
            #pragma unroll
            for (int j = 0; j < 4; ++j) {
                float4 tv = ldg4(qp + 4 * j);
                qv[qq][4 * j + 0] = tv.x * sc;
                qv[qq][4 * j + 1] = tv.y * sc;
                qv[qq][4 * j + 2] = tv.z * sc;
                qv[qq][4 * j + 3] = tv.w * sc;
            }
        }
    }

    float out[4][16];
    #pragma unroll
    for (int qq = 0; qq < 4; ++qq)
        #pragma unroll
        for (int d = 0; d < 16; ++d) out[qq][d] = 0.f;
    float ls[4] = {0.f, 0.f, 0.f, 0.f};

    // per-node mask dword (4 q bytes) for this lane
    const unsigned int* mbase = maskTu + (((size_t)(b * NNn + nbase) * NQn) >> 2) + lane;

    for (int t = 0; t < 4; ++t) {
        __syncthreads();
        {   // stage 32-node K/V tile: 2 f4/thread each, fully coalesced, linear
            const float* kg = K + ((size_t)(b * NNn + nbase + t * 32)) * 128;
            const float* vg = V + ((size_t)(b * NNn + nbase + t * 32)) * 128;
            float4 k0 = ldg4(kg + tid * 4);
            float4 k1 = ldg4(kg + (tid + 512) * 4);
            float4 v0 = ldg4(vg + tid * 4);
            float4 v1 = ldg4(vg + (tid + 512) * 4);
            *reinterpret_cast<float4*>(&Ks[tid * 4]) = k0;
            *reinterpret_cast<float4*>(&Ks[(tid + 512) * 4]) = k1;
            *reinterpret_cast<float4*>(&Vs[tid * 4]) = v0;
            *reinterpret_cast<float4*>(&Vs[(tid + 512) * 4]) = v1;
        }
        __syncthreads();

        const float* kbase = &Ks[h * 16];
        const float* vbase = &Vs[h * 16];
        for (int n = 0; n < 32; ++n) {
            const float* kr = kbase + n * 128;
            const float* vr = vbase + n * 128;
            float kf[16], vf[16];
            *reinterpret_cast<float4*>(&kf[0])  = *reinterpret_cast<const float4*>(kr);
            *reinterpret_cast<float4*>(&kf[4])  = *reinterpret_cast<const float4*>(kr + 4);
            *reinterpret_cast<float4*>(&kf[8])  = *reinterpret_cast<const float4*>(kr + 8);
            *reinterpret_cast<float4*>(&kf[12]) = *reinterpret_cast<const float4*>(kr + 12);
            *reinterpret_cast<float4*>(&vf[0])  = *reinterpret_cast<const float4*>(vr);
            *reinterpret_cast<float4*>(&vf[4])  = *reinterpret_cast<const float4*>(vr + 4);
            *reinterpret_cast<float4*>(&vf[8])  = *reinterpret_cast<const float4*>(vr + 8);
            *reinterpret_cast<float4*>(&vf[12]) = *reinterpret_cast<const float4*>(vr + 12);
            unsigned int m4 = mbase[(t * 32 + n) * (NQn / 4)];

            float p[4];
            #pragma unroll
            for (int qq = 0; qq < 4; ++qq) {
                float aP = qv[qq][0]*kf[0] + qv[qq][1]*kf[1] + qv[qq][2]*kf[2] + qv[qq][3]*kf[3];
                float aQ = qv[qq][4]*kf[4] + qv[qq][5]*kf[5] + qv[qq][6]*kf[6] + qv[qq][7]*kf[7];
                float aR = qv[qq][8]*kf[8] + qv[qq][9]*kf[9] + qv[qq][10]*kf[10] + qv[qq][11]*kf[11];
                float aS = qv[qq][12]*kf[12] + qv[qq][13]*kf[13] + qv[qq][14]*kf[14] + qv[qq][15]*kf[15];
                p[qq] = exp2f((aP + aQ) + (aR + aS));
            }
            p[0] = (m4 & 0x000000ffu) ? 0.f : p[0];   // masked -> 0
            p[1] = (m4 & 0x0000ff00u) ? 0.f : p[1];
            p[2] = (m4 & 0x00ff0000u) ? 0.f : p[2];
            p[3] = (m4 & 0xff000000u) ? 0.f : p[3];
            ls[0] += p[0]; ls[1] += p[1]; ls[2] += p[2]; ls[3] += p[3];
            #pragma unroll
            for (int d = 0; d < 16; ++d) {
                out[0][d] += p[0] * vf[d];
                out[1][d] += p[1] * vf[d];
                out[2][d] += p[2] * vf[d];
                out[3][d] += p[3] * vf[d];
            }
        }
    }

    float* P = (ns == 0) ? P0 : (ns == 1) ? P1 : (ns == 2) ? P2 : P3;
    float* L = (ns == 0) ? L0 : (ns == 1) ? L1 : (ns == 2) ? L2 : L3;
    #pragma unroll
    for (int qq = 0; qq < 4; ++qq) {
        float* op = P + ((size_t)(b * NQn + 4 * lane + qq)) * 128 + h * 16;
        *reinterpret_cast<float4*>(op)      = make_float4(out[qq][0],  out[qq][1],  out[qq][2],  out[qq][3]);
        *reinterpret_cast<float4*>(op + 4)  = make_float4(out[qq][4],  out[qq][5],  out[qq][6],  out[qq][7]);
        *reinterpret_cast<float4*>(op + 8)  = make_float4(out[qq][8],  out[qq][9],  out[qq][10], out[qq][11]);
        *reinterpret_cast<float4*>(op + 12) = make_float4(out[qq][12], out[qq][13], out[qq][14], out[qq][15]);
        L[(b * NQn + 4 * lane + qq) * 8 + h] = ls[qq];
    }
}

// ---------------------------------------------------------------------------
// attn_merge: ATT = (P0+P1+P2+P3)/(L0+..+L3); fully-masked rows -> V[b][node0].
// P0 aliases ATT (per-thread read-then-write, safe). grid 2048 x 256.
// ---------------------------------------------------------------------------
__global__ __launch_bounds__(256, 4)
void attn_merge(const float* __restrict__ P0, const float* __restrict__ P1,
                const float* __restrict__ P2, const float* __restrict__ P3,
                const float* __restrict__ L0, const float* __restrict__ L1,
                const float* __restrict__ L2, const float* __restrict__ L3,
                const float* __restrict__ V, float* __restrict__ ATT)
{
    const int idx = blockIdx.x * 256 + threadIdx.x;  // f4 index over B*NQ*32
    const int row = idx >> 5;                        // b*NQ + q
    const int f4i = idx & 31;
    const int hh  = f4i >> 2;
    const int b   = row >> 8;
    const float l = (L0[row * 8 + hh] + L1[row * 8 + hh])
                  + (L2[row * 8 + hh] + L3[row * 8 + hh]);
    float4 a = ldg4(P0 + (size_t)row * 128 + f4i * 4);
    float4 c = ldg4(P1 + (size_t)row * 128 + f4i * 4);
    float4 d = ldg4(P2 + (size_t)row * 128 + f4i * 4);
    float4 e = ldg4(P3 + (size_t)row * 128 + f4i * 4);
    float4 r;
    if (l == 0.0f) {
        r = ldg4(V + (size_t)b * NNn * 128 + f4i * 4);   // node 0, one-hot weights
    } else {
        float inv = __builtin_amdgcn_rcpf(l);
        r = make_float4((a.x + c.x + d.x + e.x) * inv, (a.y + c.y + d.y + e.y) * inv,
                        (a.z + c.z + d.z + e.z) * inv, (a.w + c.w + d.w + e.w) * inv);
    }
    *reinterpret_cast<float4*>(ATT + (size_t)row * 128 + f4i * 4) = r;
}

// ---------------------------------------------------------------------------
// final_kernel (R3 version): probs = softmax(10*tanh(MH @ EN^T/sqrt(128))+mask).
// grid B*NQ/64, block 512 (8 waves): 64 q-rows (2/thread), full 512 m.
// EN m-tiles of 128 in 64KB swizzled LDS; MH rows via L1. Fixed softmax shift
// (logits bounded by tanh clip); pr registers statically indexed.
// ---------------------------------------------------------------------------
__global__ __launch_bounds__(512, 2)
void final_kernel(const float* __restrict__ MH, const float* __restrict__ EN,
                  const float* __restrict__ mask, float* __restrict__ OUT)
{
    __shared__ float ENs[128 * 128];
    const int tid = threadIdx.x;
    const int qg = tid >> 4;          // 0..31 (2 q-rows each)
    const int mg = tid & 15;          // 0..15 (m = mg + 16c)
    const int b  = blockIdx.x >> 2;
    const int q0 = (blockIdx.x & 3) * 64;

    const float* mhbase = MH + (b * NQn + q0) * 128;
    float pr[2][32];
    float psum[2] = {0.f, 0.f};
    const int msw = mg & 7;

    #pragma unroll
    for (int t = 0; t < 4; ++t) {
        const int m0 = t * 128;
        __syncthreads();
        #pragma unroll
        for (int i = 0; i < 8; ++i) {
            int idx = tid + 512 * i;
            int r = idx >> 5;
            int c4 = idx & 31;
            float4 v = ldg4(EN + (b * NNn + m0 + r) * 128 + c4 * 4);
            *reinterpret_cast<float4*>(&ENs[r * 128 + ((c4 ^ (r & 7)) << 2)]) = v;
        }
        __syncthreads();

        float acc[2][8];
        #pragma unroll
        for (int qq = 0; qq < 2; ++qq)
            #pragma unroll
            for (int c = 0; c < 8; ++c) acc[qq][c] = 0.f;

        #pragma unroll 4
        for (int k4 = 0; k4 < 32; ++k4) {
            float4 a0 = ldg4(mhbase + (qg * 2 + 0) * 128 + k4 * 4);
            float4 a1 = ldg4(mhbase + (qg * 2 + 1) * 128 + k4 * 4);
            float4 bv[8];
            #pragma unroll
            for (int c = 0; c < 8; ++c)
                bv[c] = *reinterpret_cast<const float4*>(&ENs[(mg + 16 * c) * 128 + ((k4 ^ msw) << 2)]);
            #pragma unroll
            for (int c = 0; c < 8; ++c) {
                acc[0][c] += a0.x*bv[c].x + a0.y*bv[c].y + a0.z*bv[c].z + a0.w*bv[c].w;
                acc[1][c] += a1.x*bv[c].x + a1.y*bv[c].y + a1.z*bv[c].z + a1.w*bv[c].w;
            }
        }

        #pragma unroll
        for (int qq = 0; qq < 2; ++qq) {
            const int q = q0 + qg * 2 + qq;
            const float* mrow = mask + (b * NQn + q) * NNn + m0;
            #pragma unroll
            for (int c = 0; c < 8; ++c) {
                int m = mg + 16 * c;
                float s2 = acc[qq][c] * INV_SQRT_EMB;
                float e  = exp2f(s2 * (2.0f * LOG2E));
                float rc = __builtin_amdgcn_rcpf(e + 1.0f);
                float mv = mrow[m];
                float pv = exp2f((mv - 20.0f * rc) * LOG2E);
                pr[qq][t * 8 + c] = pv;
                psum[qq] += pv;
            }
        }
    }

    #pragma unroll
    for (int qq = 0; qq < 2; ++qq) {
        float s = psum[qq];
        s += __shfl_xor(s, 1);
        s += __shfl_xor(s, 2);
        s += __shfl_xor(s, 4);
        s += __shfl_xor(s, 8);
        psum[qq] = s;
    }

    #pragma unroll
    for (int qq = 0; qq < 2; ++qq) {
        const int q = q0 + qg * 2 + qq;
        float* orow = OUT + (b * NQn + q) * NNn;
        if (psum[qq] == 0.0f) {
            #pragma unroll
            for (int t = 0; t < 4; ++t)
                #pragma unroll
                for (int c = 0; c < 8; ++c) {
                    int m = t * 128 + mg + 16 * c;
                    orow[m] = (m == 0) ? 1.0f : 0.0f;
                }
        } else {
            float inv = __builtin_amdgcn_rcpf(psum[qq]);
            #pragma unroll
            for (int t = 0; t < 4; ++t)
                #pragma unroll
                for (int c = 0; c < 8; ++c)
                    orow[t * 128 + mg + 16 * c] = pr[qq][t * 8 + c] * inv;
        }
    }
}

// ---------------------------------------------------------------------------
extern "C" void kernel_launch(void* const* d_in, const int* in_sizes, int n_in,
                              void* d_out, int out_size, void* d_ws, size_t ws_size,
                              hipStream_t stream) {
    const float* enc_last  = (const float*)d_in[0];   // [B,NQ,128]
    const float* attr      = (const float*)d_in[1];   // [B,NQ,1]
    const float* enc_nodes = (const float*)d_in[2];   // [B,NN,128]
    const float* mask      = (const float*)d_in[3];   // [B,NQ,NN]
    const float* Wq        = (const float*)d_in[4];   // [129,128]
    const float* Wk        = (const float*)d_in[5];   // [128,128]
    const float* Wv        = (const float*)d_in[6];   // [128,128]
    const float* Wcomb     = (const float*)d_in[7];   // [128,128]
    const float* bcomb     = (const float*)d_in[8];   // [128]
    float* out = (float*)d_out;

    float* Kbuf = (float*)d_ws;                         // [B*NN,128] 16.8MB
    float* Vbuf = Kbuf + (size_t)NB * NNn * 128;        // [B*NN,128] 16.8MB
    float* Qbuf = Vbuf + (size_t)NB * NNn * 128;        // [B*NQ,128]  8.4MB
    float* ATT  = Qbuf + (size_t)NB * NQn * 128;        // [B*NQ,128]  8.4MB (= P0)
    float* P1   = ATT  + (size_t)NB * NQn * 128;        // 8.4MB (MH aliases after merge)
    float* P2   = P1   + (size_t)NB * NQn * 128;        // 8.4MB
    float* P3   = P2   + (size_t)NB * NQn * 128;        // 8.4MB
    float* L0   = P3   + (size_t)NB * NQn * 128;        // 0.5MB
    float* L1   = L0   + (size_t)NB * NQn * 8;
    float* L2   = L1   + (size_t)NB * NQn * 8;
    float* L3   = L2   + (size_t)NB * NQn * 8;
    unsigned char* maskT8 = (unsigned char*)(L3 + (size_t)NB * NQn * 8);  // 8.4MB u8
    float* MH   = P1;   // alias: P1 dead after attn_merge; proj-comb writes, final reads

    // mask -> transposed u8 [b][n][q]
    mask_transpose<<<dim3(NB, NQn / 64, NNn / 64), 256, 0, stream>>>(mask, maskT8);
    // K,V projections (dual-pass over shared X tile)
    proj_kernel<<<dim3(NB * NNn / 64, 2), 256, 0, stream>>>(
        enc_nodes, Wk, Wv, nullptr, nullptr, nullptr, Kbuf, Vbuf);
    // Q projection (concat attr handled as rank-1 term with Wq row 128)
    proj_kernel<<<dim3(NB * NQn / 64, 2), 256, 0, stream>>>(
        enc_last, Wq, nullptr, Wq + 128 * 128, attr, nullptr, Qbuf, nullptr);
    // masked multi-head attention, 4 q-rows/lane, 4 node-splits
    attn_kernel<<<dim3(NB, 4), 512, 0, stream>>>(
        Qbuf, Kbuf, Vbuf, (const unsigned int*)maskT8,
        ATT, P1, P2, P3, L0, L1, L2, L3);
    // merge node-splits (P0 aliases ATT)
    attn_merge<<<dim3(NB * NQn * 32 / 256), 256, 0, stream>>>(
        ATT, P1, P2, P3, L0, L1, L2, L3, Vbuf, ATT);
    // combine projection + bias
    proj_kernel<<<dim3(NB * NQn / 64, 2), 256, 0, stream>>>(
        ATT, Wcomb, nullptr, nullptr, nullptr, bcomb, MH, nullptr);
    // compatibility score + tanh clip + masked softmax
    final_kernel<<<dim3(NB * NQn / 64), 512, 0, stream>>>(
        MH, enc_nodes, mask, out);
}